// Round 5
// baseline (144.943 us; speedup 1.0000x reference)
//
#include <hip/hip_runtime.h>
#include <hip/hip_fp16.h>
#include <math.h>

// ---------------------------------------------------------------------------
// Fully-fused SAFM, one launch. Tile = 16w x 2h pixels, grid 2048 = 4b*64th*8tw.
// Each 2x2 pixel block (eb 0..7) shares one k (half-res) and one v (quarter-res)
// pixel => one E[i][j] = exp(v_i k_j)/denom_j matrix per eb.
//
// Phases: P1 {stage p1 (6x12 halo, zero-OOB) + s0 dwconv from global -> s0s}
//         P2 {k dwconv -> registers, v dwconv (p2 = max4(p1s) on the fly) -> vsh}
//         P3 {E columns, fold 1/denom, pack fp16 -> Ebf (overlays p1s)}
//         P4 {qkv[i] = sum_j En[i,j] q[p,j] -> qkvs}
//         P5 {1x1 conv (wa global) + exact GELU + mul x -> out}
// LDS 25.5 KB -> 5-6 blocks/CU (vs 2 before). 4 barriers (vs 5).
// ---------------------------------------------------------------------------

__device__ __forceinline__ float2 h2f2(unsigned int u) {
  __half2 h = *reinterpret_cast<__half2*>(&u);
  return __half22float2(h);
}
__device__ __forceinline__ unsigned int f2h2(float a, float b) {
  __half2 h = __floats2half2_rn(a, b);
  return *reinterpret_cast<unsigned int*>(&h);
}

__global__ __launch_bounds__(256, 5) void fused_safm(
    const float* __restrict__ x,
    const float* __restrict__ w0, const float* __restrict__ b0,
    const float* __restrict__ w1, const float* __restrict__ b1,
    const float* __restrict__ w2, const float* __restrict__ b2,
    const float* __restrict__ wa, const float* __restrict__ ba,
    float* __restrict__ out) {
  int bid = blockIdx.x;
  int tw = bid & 7, th = (bid >> 3) & 63, b = bid >> 9;
  int t = threadIdx.x;
  int h4 = th >> 1;

  // Ebf (fp16x2 words): [eb][ip][j], ip stride 32 words, eb stride 516 words
  // (516 mod 32 = 4 -> the 8 ebs start 4 banks apart: conflict-free b128 reads)
  __shared__ __align__(16) unsigned int regA[4128];   // 16.5 KB, overlays p1s
  __shared__ __align__(16) float s0s[1056];           // [p][c] stride 33
  __shared__ __align__(16) float vsh[288];            // [eb][i] stride 36
  __shared__ __align__(16) float qkvs[1056];          // [p][i] stride 33
  float* p1s = (float*)regA;                          // [c][6][12] stride 73

  // ---- P1a: stage p1 tile: rows 2h4-2..2h4+3, cols 8tw-2..8tw+9, OOB=0 ----
  {
#pragma unroll
    for (int kk = 0; kk < 9; ++kk) {
      int idx = t + kk * 256;                    // 2304 cells = 32c * 72
      int c = idx / 72, rem = idx % 72;
      int r = rem / 12, w = rem % 12;
      int pr = 2 * h4 - 2 + r, pc = 8 * tw - 2 + w;
      float v = 0.f;
      if ((unsigned)pr < 64u && (unsigned)pc < 64u) {
        const float* xp = x + ((size_t)(b * 32 + c) << 14) + 2 * pr * 128 + 2 * pc;
        float2 r0 = *(const float2*)xp;
        float2 r1 = *(const float2*)(xp + 128);
        v = fmaxf(fmaxf(r0.x, r0.y), fmaxf(r1.x, r1.y));
      }
      p1s[c * 73 + r * 12 + w] = v;
    }
  }
  // ---- P1b: s0 dwconv (full res) from global -> s0s (pixel-major) ----
  {
    int c = t >> 3, gg = t & 7;
    int hh = gg >> 2, wb = (gg & 3) * 4;
    const float* xp = x + ((size_t)(b * 32 + c) << 14);
    const float* wc = w0 + c * 9;
    float wv[9];
#pragma unroll
    for (int q = 0; q < 9; ++q) wv[q] = wc[q];
    float bz = b0[c];
    float a0 = bz, a1 = bz, a2 = bz, a3 = bz;
    int cbase = 16 * tw + wb;
#pragma unroll
    for (int dr = -1; dr <= 1; ++dr) {
      int row = 2 * th + hh + dr;
      if ((unsigned)row >= 128u) continue;
      const float* rp = xp + row * 128 + cbase;
      float cm1 = (cbase > 0)       ? rp[-1] : 0.f;
      float4 c03 = *(const float4*)rp;
      float c4  = (cbase + 4 < 128) ? rp[4]  : 0.f;
      float wA = wv[(dr + 1) * 3], wB = wv[(dr + 1) * 3 + 1], wC = wv[(dr + 1) * 3 + 2];
      a0 = fmaf(wA, cm1,   fmaf(wB, c03.x, fmaf(wC, c03.y, a0)));
      a1 = fmaf(wA, c03.x, fmaf(wB, c03.y, fmaf(wC, c03.z, a1)));
      a2 = fmaf(wA, c03.y, fmaf(wB, c03.z, fmaf(wC, c03.w, a2)));
      a3 = fmaf(wA, c03.z, fmaf(wB, c03.w, fmaf(wC, c4,    a3)));
    }
    int pb = hh * 16 + wb;
    s0s[(pb)     * 33 + c] = a0;
    s0s[(pb + 1) * 33 + c] = a1;
    s0s[(pb + 2) * 33 + c] = a2;
    s0s[(pb + 3) * 33 + c] = a3;
  }
  __syncthreads();

  // ---- P2: k dwconv -> register; v dwconv (p2 from p1s max4) -> vsh ----
  int ebT = t >> 5, jT = t & 31;
  float kreg;
  {
    const float* wc = w1 + jT * 9;
    const float* Pk = p1s + jT * 73 + ((th & 1) + 1) * 12 + ebT + 1;
    float acc = b1[jT];
    acc = fmaf(wc[0], Pk[0],  fmaf(wc[1], Pk[1],  fmaf(wc[2], Pk[2],  acc)));
    acc = fmaf(wc[3], Pk[12], fmaf(wc[4], Pk[13], fmaf(wc[5], Pk[14], acc)));
    acc = fmaf(wc[6], Pk[24], fmaf(wc[7], Pk[25], fmaf(wc[8], Pk[26], acc)));
    kreg = acc;
  }
  {
    const float* wc = w2 + jT * 9;
    const float* P = p1s + jT * 73;
    int cb0 = 2 * (ebT >> 1);
    float acc = b2[jT];
#pragma unroll
    for (int hq = 0; hq < 3; ++hq) {
      const float* Pr = P + 2 * hq * 12;
#pragma unroll
      for (int wq = 0; wq < 3; ++wq) {
        int cb = cb0 + 2 * wq;
        float p2v = fmaxf(fmaxf(Pr[cb], Pr[cb + 1]), fmaxf(Pr[cb + 12], Pr[cb + 13]));
        acc = fmaf(wc[hq * 3 + wq], p2v, acc);
      }
    }
    vsh[ebT * 36 + jT] = acc;
  }
  __syncthreads();

  // ---- P3: E column j of block eb, scaled by 1/denom, packed fp16 ----
  {
    float vv[32];
    const float4* v4 = (const float4*)(vsh + ebT * 36);
#pragma unroll
    for (int iq = 0; iq < 8; ++iq) {
      float4 q_ = v4[iq];
      vv[4 * iq] = q_.x; vv[4 * iq + 1] = q_.y; vv[4 * iq + 2] = q_.z; vv[4 * iq + 3] = q_.w;
    }
    float vmax = vv[0], vmin = vv[0];
#pragma unroll
    for (int i = 1; i < 32; ++i) {
      vmax = fmaxf(vmax, vv[i]);
      vmin = fminf(vmin, vv[i]);
    }
    const float L2E = 1.4426950408889634f;
    float m  = (kreg >= 0.f) ? kreg * vmax : kreg * vmin;
    float kl = kreg * L2E;
    float nm = -m * L2E;
    float e[32];
    float d0 = 0.f, d1 = 0.f, d2 = 0.f, d3 = 0.f;
#pragma unroll
    for (int i = 0; i < 32; i += 4) {
      e[i]     = __builtin_amdgcn_exp2f(fmaf(vv[i],     kl, nm)); d0 += e[i];
      e[i + 1] = __builtin_amdgcn_exp2f(fmaf(vv[i + 1], kl, nm)); d1 += e[i + 1];
      e[i + 2] = __builtin_amdgcn_exp2f(fmaf(vv[i + 2], kl, nm)); d2 += e[i + 2];
      e[i + 3] = __builtin_amdgcn_exp2f(fmaf(vv[i + 3], kl, nm)); d3 += e[i + 3];
    }
    float rd = __fdividef(1.f, (d0 + d1) + (d2 + d3));
    unsigned int* EB = regA + ebT * 516 + jT;
#pragma unroll
    for (int ip = 0; ip < 16; ++ip)
      EB[ip * 32] = f2h2(e[2 * ip] * rd, e[2 * ip + 1] * rd);
  }
  __syncthreads();

  // ---- P4: qkv[i] = sum_j En[i,j] * q[p,j] ----
  {
    int p = t & 31, ic = t >> 5;               // pixel p, i-chunk ic (4 i's)
    int eb = (p & 15) >> 1;
    const unsigned int* EB = regA + eb * 516;
    const float* qrow = s0s + p * 33;
    float a0 = 0.f, a1 = 0.f, a2 = 0.f, a3 = 0.f;
#pragma unroll
    for (int jw = 0; jw < 8; ++jw) {
      uint4 wA = *(const uint4*)(EB + (2 * ic)     * 32 + jw * 4);
      uint4 wB = *(const uint4*)(EB + (2 * ic + 1) * 32 + jw * 4);
      float q0 = qrow[4 * jw], q1 = qrow[4 * jw + 1];
      float q2 = qrow[4 * jw + 2], q3 = qrow[4 * jw + 3];
      float2 f;
      f = h2f2(wA.x); a0 = fmaf(f.x, q0, a0); a1 = fmaf(f.y, q0, a1);
      f = h2f2(wA.y); a0 = fmaf(f.x, q1, a0); a1 = fmaf(f.y, q1, a1);
      f = h2f2(wA.z); a0 = fmaf(f.x, q2, a0); a1 = fmaf(f.y, q2, a1);
      f = h2f2(wA.w); a0 = fmaf(f.x, q3, a0); a1 = fmaf(f.y, q3, a1);
      f = h2f2(wB.x); a2 = fmaf(f.x, q0, a2); a3 = fmaf(f.y, q0, a3);
      f = h2f2(wB.y); a2 = fmaf(f.x, q1, a2); a3 = fmaf(f.y, q1, a3);
      f = h2f2(wB.z); a2 = fmaf(f.x, q2, a2); a3 = fmaf(f.y, q2, a3);
      f = h2f2(wB.w); a2 = fmaf(f.x, q3, a2); a3 = fmaf(f.y, q3, a3);
    }
    float* qd = qkvs + p * 33 + ic * 4;
    qd[0] = a0; qd[1] = a1; qd[2] = a2; qd[3] = a3;
  }
  __syncthreads();

  // ---- P5: 1x1 conv (wa from global, L1 broadcast) + GELU + mul x ----
  {
    int o = t >> 3, g = t & 7;
    int hh = g >> 2, wb = (g & 3) * 4;
    const float* wo = wa + o * 32;
    const float* q0 = qkvs + (hh * 16 + wb)     * 33;
    const float* q1 = qkvs + (hh * 16 + wb + 1) * 33;
    const float* q2 = qkvs + (hh * 16 + wb + 2) * 33;
    const float* q3 = qkvs + (hh * 16 + wb + 3) * 33;
    float bz = ba[o];
    float y0 = bz, y1 = bz, y2 = bz, y3 = bz;
#pragma unroll
    for (int i = 0; i < 32; ++i) {
      float w = wo[i];
      y0 = fmaf(w, q0[i], y0);
      y1 = fmaf(w, q1[i], y1);
      y2 = fmaf(w, q2[i], y2);
      y3 = fmaf(w, q3[i], y3);
    }
    const float RS2 = 0.70710678118654752f;
    float g0 = 0.5f * y0 * (1.f + erff(y0 * RS2));
    float g1 = 0.5f * y1 * (1.f + erff(y1 * RS2));
    float g2 = 0.5f * y2 * (1.f + erff(y2 * RS2));
    float g3 = 0.5f * y3 * (1.f + erff(y3 * RS2));
    size_t ob = (((size_t)(b * 32 + o) * 128) + (2 * th + hh)) * 128 + 16 * tw + wb;
    float4 xv = *(const float4*)(x + ob);
    float4 r;
    r.x = g0 * xv.x; r.y = g1 * xv.y; r.z = g2 * xv.z; r.w = g3 * xv.w;
    *(float4*)(out + ob) = r;
  }
}

// ---------------------------------------------------------------------------
extern "C" void kernel_launch(void* const* d_in, const int* in_sizes, int n_in,
                              void* d_out, int out_size, void* d_ws, size_t ws_size,
                              hipStream_t stream) {
  const float* x  = (const float*)d_in[0];
  const float* w0 = (const float*)d_in[1];
  const float* b0 = (const float*)d_in[2];
  const float* w1 = (const float*)d_in[3];
  const float* b1 = (const float*)d_in[4];
  const float* w2 = (const float*)d_in[5];
  const float* b2 = (const float*)d_in[6];
  const float* wa = (const float*)d_in[7];
  const float* ba = (const float*)d_in[8];
  float* out = (float*)d_out;

  fused_safm<<<2048, 256, 0, stream>>>(x, w0, b0, w1, b1, w2, b2, wa, ba, out);
}

// Round 6
// 109.846 us; speedup vs baseline: 1.3195x; 1.3195x over previous
//
#include <hip/hip_runtime.h>
#include <hip/hip_fp16.h>
#include <math.h>

// ---------------------------------------------------------------------------
// Fully-fused SAFM, one launch. Tile = 16w x 2h pixels, grid 2048 = 4b*64th*8tw.
// Each 2x2 pixel block (eb 0..7) shares one k (half-res) and one v (quarter-res)
// pixel => one E[i][j] = exp(v_i k_j)/denom_j matrix per eb.
//
// Phases: P1 {stage p1 (6x12 halo, zero-OOB) + s0 dwconv from global -> s0s}
//         P2 {k dwconv -> registers, v dwconv (p2 = max4(p1s) on the fly) -> vsh}
//         P3 {E columns UNSCALED, streamed exp->fp16 pack (no reg arrays);
//             1/denom -> rds[eb][j]}
//         P4 {qkv[i] = sum_j E[i,j] * (q[p,j]*rd[j]) -> qkvs}
//         P5 {1x1 conv (wa global) + exact GELU + mul x -> out}
// LDS 27.2 KB; __launch_bounds__(256,4) -> VGPR cap 128, no spills (R5 bug:
// min-waves=5 forced VGPR=48 and 240 MB of scratch spill traffic).
// ---------------------------------------------------------------------------

__device__ __forceinline__ float2 h2f2(unsigned int u) {
  __half2 h = *reinterpret_cast<__half2*>(&u);
  return __half22float2(h);
}
__device__ __forceinline__ unsigned int f2h2(float a, float b) {
  __half2 h = __floats2half2_rn(a, b);
  return *reinterpret_cast<unsigned int*>(&h);
}

__global__ __launch_bounds__(256, 4) void fused_safm(
    const float* __restrict__ x,
    const float* __restrict__ w0, const float* __restrict__ b0,
    const float* __restrict__ w1, const float* __restrict__ b1,
    const float* __restrict__ w2, const float* __restrict__ b2,
    const float* __restrict__ wa, const float* __restrict__ ba,
    float* __restrict__ out) {
  int bid = blockIdx.x;
  int tw = bid & 7, th = (bid >> 3) & 63, b = bid >> 9;
  int t = threadIdx.x;
  int h4 = th >> 1;

  // Ebf (fp16x2 words): [eb][ip][j], ip stride 32 words, eb stride 516 words
  // (516 mod 32 = 4 -> the 8 ebs start 4 banks apart: conflict-free b128 reads)
  __shared__ __align__(16) unsigned int regA[4128];   // 16.5 KB, overlays p1s
  __shared__ __align__(16) float s0s[1056];           // [p][c] stride 33
  __shared__ __align__(16) float vsh[288];            // [eb][i] stride 36
  __shared__ __align__(16) float qkvs[1056];          // [p][i] stride 33
  __shared__ __align__(16) float rds[264];            // [eb][j] stride 33
  float* p1s = (float*)regA;                          // [c][6][12] stride 73

  // ---- P1a: stage p1 tile: rows 2h4-2..2h4+3, cols 8tw-2..8tw+9, OOB=0 ----
  {
#pragma unroll
    for (int kk = 0; kk < 9; ++kk) {
      int idx = t + kk * 256;                    // 2304 cells = 32c * 72
      int c = idx / 72, rem = idx % 72;
      int r = rem / 12, w = rem % 12;
      int pr = 2 * h4 - 2 + r, pc = 8 * tw - 2 + w;
      float v = 0.f;
      if ((unsigned)pr < 64u && (unsigned)pc < 64u) {
        const float* xp = x + ((size_t)(b * 32 + c) << 14) + 2 * pr * 128 + 2 * pc;
        float2 r0 = *(const float2*)xp;
        float2 r1 = *(const float2*)(xp + 128);
        v = fmaxf(fmaxf(r0.x, r0.y), fmaxf(r1.x, r1.y));
      }
      p1s[c * 73 + r * 12 + w] = v;
    }
  }
  // ---- P1b: s0 dwconv (full res) from global -> s0s (pixel-major) ----
  {
    int c = t >> 3, gg = t & 7;
    int hh = gg >> 2, wb = (gg & 3) * 4;
    const float* xp = x + ((size_t)(b * 32 + c) << 14);
    const float* wc = w0 + c * 9;
    float wv[9];
#pragma unroll
    for (int q = 0; q < 9; ++q) wv[q] = wc[q];
    float bz = b0[c];
    float a0 = bz, a1 = bz, a2 = bz, a3 = bz;
    int cbase = 16 * tw + wb;
#pragma unroll
    for (int dr = -1; dr <= 1; ++dr) {
      int row = 2 * th + hh + dr;
      if ((unsigned)row >= 128u) continue;
      const float* rp = xp + row * 128 + cbase;
      float cm1 = (cbase > 0)       ? rp[-1] : 0.f;
      float4 c03 = *(const float4*)rp;
      float c4  = (cbase + 4 < 128) ? rp[4]  : 0.f;
      float wA = wv[(dr + 1) * 3], wB = wv[(dr + 1) * 3 + 1], wC = wv[(dr + 1) * 3 + 2];
      a0 = fmaf(wA, cm1,   fmaf(wB, c03.x, fmaf(wC, c03.y, a0)));
      a1 = fmaf(wA, c03.x, fmaf(wB, c03.y, fmaf(wC, c03.z, a1)));
      a2 = fmaf(wA, c03.y, fmaf(wB, c03.z, fmaf(wC, c03.w, a2)));
      a3 = fmaf(wA, c03.z, fmaf(wB, c03.w, fmaf(wC, c4,    a3)));
    }
    int pb = hh * 16 + wb;
    s0s[(pb)     * 33 + c] = a0;
    s0s[(pb + 1) * 33 + c] = a1;
    s0s[(pb + 2) * 33 + c] = a2;
    s0s[(pb + 3) * 33 + c] = a3;
  }
  __syncthreads();

  // ---- P2: k dwconv -> register; v dwconv (p2 from p1s max4) -> vsh ----
  int ebT = t >> 5, jT = t & 31;
  float kreg;
  {
    const float* wc = w1 + jT * 9;
    const float* Pk = p1s + jT * 73 + ((th & 1) + 1) * 12 + ebT + 1;
    float acc = b1[jT];
    acc = fmaf(wc[0], Pk[0],  fmaf(wc[1], Pk[1],  fmaf(wc[2], Pk[2],  acc)));
    acc = fmaf(wc[3], Pk[12], fmaf(wc[4], Pk[13], fmaf(wc[5], Pk[14], acc)));
    acc = fmaf(wc[6], Pk[24], fmaf(wc[7], Pk[25], fmaf(wc[8], Pk[26], acc)));
    kreg = acc;
  }
  {
    const float* wc = w2 + jT * 9;
    const float* P = p1s + jT * 73;
    int cb0 = 2 * (ebT >> 1);
    float acc = b2[jT];
#pragma unroll
    for (int hq = 0; hq < 3; ++hq) {
      const float* Pr = P + 2 * hq * 12;
#pragma unroll
      for (int wq = 0; wq < 3; ++wq) {
        int cb = cb0 + 2 * wq;
        float p2v = fmaxf(fmaxf(Pr[cb], Pr[cb + 1]), fmaxf(Pr[cb + 12], Pr[cb + 13]));
        acc = fmaf(wc[hq * 3 + wq], p2v, acc);
      }
    }
    vsh[ebT * 36 + jT] = acc;
  }
  __syncthreads();

  // ---- P3: E column j of block eb (unscaled), streamed fp16 pack ----
  {
    const float* vb = vsh + ebT * 36;
    const float4* v4 = (const float4*)vb;
    float4 q0 = v4[0];
    float vmax = fmaxf(fmaxf(q0.x, q0.y), fmaxf(q0.z, q0.w));
    float vmin = fminf(fminf(q0.x, q0.y), fminf(q0.z, q0.w));
#pragma unroll
    for (int iq = 1; iq < 8; ++iq) {
      float4 q_ = v4[iq];
      vmax = fmaxf(vmax, fmaxf(fmaxf(q_.x, q_.y), fmaxf(q_.z, q_.w)));
      vmin = fminf(vmin, fminf(fminf(q_.x, q_.y), fminf(q_.z, q_.w)));
    }
    const float L2E = 1.4426950408889634f;
    float m  = (kreg >= 0.f) ? kreg * vmax : kreg * vmin;
    float kl = kreg * L2E;
    float nm = -m * L2E;
    float d0 = 0.f, d1 = 0.f;
    unsigned int* EB = regA + ebT * 516 + jT;
#pragma unroll
    for (int ip = 0; ip < 16; ++ip) {
      float2 vp = *(const float2*)(vb + 2 * ip);
      float e0 = __builtin_amdgcn_exp2f(fmaf(vp.x, kl, nm));
      float e1 = __builtin_amdgcn_exp2f(fmaf(vp.y, kl, nm));
      d0 += e0; d1 += e1;
      EB[ip * 32] = f2h2(e0, e1);
    }
    rds[ebT * 33 + jT] = __fdividef(1.f, d0 + d1);
  }
  __syncthreads();

  // ---- P4: qkv[i] = sum_j E[i,j] * (q[p,j] * rd[j]) ----
  {
    int p = t & 31, ic = t >> 5;               // pixel p, i-chunk ic (4 i's)
    int eb = (p & 15) >> 1;
    const unsigned int* EB = regA + eb * 516;
    const float* qrow = s0s + p * 33;
    const float* rdr = rds + eb * 33;
    float a0 = 0.f, a1 = 0.f, a2 = 0.f, a3 = 0.f;
#pragma unroll
    for (int jw = 0; jw < 8; ++jw) {
      uint4 wA = *(const uint4*)(EB + (2 * ic)     * 32 + jw * 4);
      uint4 wB = *(const uint4*)(EB + (2 * ic + 1) * 32 + jw * 4);
      float q0 = qrow[4 * jw]     * rdr[4 * jw];
      float q1 = qrow[4 * jw + 1] * rdr[4 * jw + 1];
      float q2 = qrow[4 * jw + 2] * rdr[4 * jw + 2];
      float q3 = qrow[4 * jw + 3] * rdr[4 * jw + 3];
      float2 f;
      f = h2f2(wA.x); a0 = fmaf(f.x, q0, a0); a1 = fmaf(f.y, q0, a1);
      f = h2f2(wA.y); a0 = fmaf(f.x, q1, a0); a1 = fmaf(f.y, q1, a1);
      f = h2f2(wA.z); a0 = fmaf(f.x, q2, a0); a1 = fmaf(f.y, q2, a1);
      f = h2f2(wA.w); a0 = fmaf(f.x, q3, a0); a1 = fmaf(f.y, q3, a1);
      f = h2f2(wB.x); a2 = fmaf(f.x, q0, a2); a3 = fmaf(f.y, q0, a3);
      f = h2f2(wB.y); a2 = fmaf(f.x, q1, a2); a3 = fmaf(f.y, q1, a3);
      f = h2f2(wB.z); a2 = fmaf(f.x, q2, a2); a3 = fmaf(f.y, q2, a3);
      f = h2f2(wB.w); a2 = fmaf(f.x, q3, a2); a3 = fmaf(f.y, q3, a3);
    }
    float* qd = qkvs + p * 33 + ic * 4;
    qd[0] = a0; qd[1] = a1; qd[2] = a2; qd[3] = a3;
  }
  __syncthreads();

  // ---- P5: 1x1 conv (wa from global, L1 broadcast) + GELU + mul x ----
  {
    int o = t >> 3, g = t & 7;
    int hh = g >> 2, wb = (g & 3) * 4;
    const float* wo = wa + o * 32;
    const float* q0 = qkvs + (hh * 16 + wb)     * 33;
    const float* q1 = qkvs + (hh * 16 + wb + 1) * 33;
    const float* q2 = qkvs + (hh * 16 + wb + 2) * 33;
    const float* q3 = qkvs + (hh * 16 + wb + 3) * 33;
    float bz = ba[o];
    float y0 = bz, y1 = bz, y2 = bz, y3 = bz;
#pragma unroll
    for (int i = 0; i < 32; ++i) {
      float w = wo[i];
      y0 = fmaf(w, q0[i], y0);
      y1 = fmaf(w, q1[i], y1);
      y2 = fmaf(w, q2[i], y2);
      y3 = fmaf(w, q3[i], y3);
    }
    const float RS2 = 0.70710678118654752f;
    float g0 = 0.5f * y0 * (1.f + erff(y0 * RS2));
    float g1 = 0.5f * y1 * (1.f + erff(y1 * RS2));
    float g2 = 0.5f * y2 * (1.f + erff(y2 * RS2));
    float g3 = 0.5f * y3 * (1.f + erff(y3 * RS2));
    size_t ob = (((size_t)(b * 32 + o) * 128) + (2 * th + hh)) * 128 + 16 * tw + wb;
    float4 xv = *(const float4*)(x + ob);
    float4 r;
    r.x = g0 * xv.x; r.y = g1 * xv.y; r.z = g2 * xv.z; r.w = g3 * xv.w;
    *(float4*)(out + ob) = r;
  }
}

// ---------------------------------------------------------------------------
extern "C" void kernel_launch(void* const* d_in, const int* in_sizes, int n_in,
                              void* d_out, int out_size, void* d_ws, size_t ws_size,
                              hipStream_t stream) {
  const float* x  = (const float*)d_in[0];
  const float* w0 = (const float*)d_in[1];
  const float* b0 = (const float*)d_in[2];
  const float* w1 = (const float*)d_in[3];
  const float* b1 = (const float*)d_in[4];
  const float* w2 = (const float*)d_in[5];
  const float* b2 = (const float*)d_in[6];
  const float* wa = (const float*)d_in[7];
  const float* ba = (const float*)d_in[8];
  float* out = (float*)d_out;

  fused_safm<<<2048, 256, 0, stream>>>(x, w0, b0, w1, b1, w2, b2, wa, ba, out);
}

// Round 8
// 106.572 us; speedup vs baseline: 1.3600x; 1.0307x over previous
//
#include <hip/hip_runtime.h>
#include <hip/hip_fp16.h>
#include <math.h>

// ---------------------------------------------------------------------------
// Fully-fused SAFM, one launch. Tile = 16w x 2h pixels, grid 2048 = 4b*64th*8tw.
// Each 2x2 pixel block (eb 0..7) shares one k (half-res) and one v (quarter-res)
// pixel => one E[i][j] = exp(v_i k_j)/denom_j matrix per eb.
//
// Phases: P1 {stage p1 (6x12 halo, zero-OOB) + s0 dwconv from global -> s0s}
//         P2 {k dwconv -> registers, v dwconv (p2 = max4(p1s) on the fly) -> vsh}
//         P3 {E columns UNSCALED, streamed exp->fp16 pack; 1/denom -> rds}
//         P4 {qkv[i] = sum_j E[i,j] * (q[p,j]*rd[j]) -> qkvs}
//         P5 {1x1 conv (wa global) + exact GELU + mul x -> out}
//
// LDS 27.2 KB. __launch_bounds__(256) with NO min-waves arg: R5/R6 showed the
// min-waves argument makes the backend spill to hit an occupancy target
// ((256,5) -> 48 VGPR + 153 MB scratch writes; (256,4) -> 64 VGPR + 47 MB).
// Natural allocation (~88 VGPR in R4) spills nothing; LDS already permits
// 5 blocks/CU.
// ---------------------------------------------------------------------------

__device__ __forceinline__ float2 h2f2(unsigned int u) {
  __half2 h = *reinterpret_cast<__half2*>(&u);
  return __half22float2(h);
}
__device__ __forceinline__ unsigned int f2h2(float a, float b) {
  __half2 h = __floats2half2_rn(a, b);
  return *reinterpret_cast<unsigned int*>(&h);
}

__global__ __launch_bounds__(256) void fused_safm(
    const float* __restrict__ x,
    const float* __restrict__ w0, const float* __restrict__ b0,
    const float* __restrict__ w1, const float* __restrict__ b1,
    const float* __restrict__ w2, const float* __restrict__ b2,
    const float* __restrict__ wa, const float* __restrict__ ba,
    float* __restrict__ out) {
  int bid = blockIdx.x;
  int tw = bid & 7, th = (bid >> 3) & 63, b = bid >> 9;
  int t = threadIdx.x;
  int h4 = th >> 1;

  // Ebf (fp16x2 words): [eb][ip][j], ip stride 32 words, eb stride 516 words
  // (516 mod 32 = 4 -> the 8 ebs start 4 banks apart: conflict-free b128 reads)
  __shared__ __align__(16) unsigned int regA[4128];   // 16.5 KB, overlays p1s
  __shared__ __align__(16) float s0s[1056];           // [p][c] stride 33
  __shared__ __align__(16) float vsh[288];            // [eb][i] stride 36
  __shared__ __align__(16) float qkvs[1056];          // [p][i] stride 33
  __shared__ __align__(16) float rds[264];            // [eb][j] stride 33
  float* p1s = (float*)regA;                          // [c][6][12] stride 73

  // ---- P1a: stage p1 tile: rows 2h4-2..2h4+3, cols 8tw-2..8tw+9, OOB=0 ----
  {
#pragma unroll
    for (int kk = 0; kk < 9; ++kk) {
      int idx = t + kk * 256;                    // 2304 cells = 32c * 72
      int c = idx / 72, rem = idx % 72;
      int r = rem / 12, w = rem % 12;
      int pr = 2 * h4 - 2 + r, pc = 8 * tw - 2 + w;
      float v = 0.f;
      if ((unsigned)pr < 64u && (unsigned)pc < 64u) {
        const float* xp = x + ((size_t)(b * 32 + c) << 14) + 2 * pr * 128 + 2 * pc;
        float2 r0 = *(const float2*)xp;
        float2 r1 = *(const float2*)(xp + 128);
        v = fmaxf(fmaxf(r0.x, r0.y), fmaxf(r1.x, r1.y));
      }
      p1s[c * 73 + r * 12 + w] = v;
    }
  }
  // ---- P1b: s0 dwconv (full res) from global -> s0s (pixel-major) ----
  {
    int c = t >> 3, gg = t & 7;
    int hh = gg >> 2, wb = (gg & 3) * 4;
    const float* xp = x + ((size_t)(b * 32 + c) << 14);
    const float* wc = w0 + c * 9;
    float wv[9];
#pragma unroll
    for (int q = 0; q < 9; ++q) wv[q] = wc[q];
    float bz = b0[c];
    float a0 = bz, a1 = bz, a2 = bz, a3 = bz;
    int cbase = 16 * tw + wb;
#pragma unroll
    for (int dr = -1; dr <= 1; ++dr) {
      int row = 2 * th + hh + dr;
      if ((unsigned)row >= 128u) continue;
      const float* rp = xp + row * 128 + cbase;
      float cm1 = (cbase > 0)       ? rp[-1] : 0.f;
      float4 c03 = *(const float4*)rp;
      float c4  = (cbase + 4 < 128) ? rp[4]  : 0.f;
      float wA = wv[(dr + 1) * 3], wB = wv[(dr + 1) * 3 + 1], wC = wv[(dr + 1) * 3 + 2];
      a0 = fmaf(wA, cm1,   fmaf(wB, c03.x, fmaf(wC, c03.y, a0)));
      a1 = fmaf(wA, c03.x, fmaf(wB, c03.y, fmaf(wC, c03.z, a1)));
      a2 = fmaf(wA, c03.y, fmaf(wB, c03.z, fmaf(wC, c03.w, a2)));
      a3 = fmaf(wA, c03.z, fmaf(wB, c03.w, fmaf(wC, c4,    a3)));
    }
    int pb = hh * 16 + wb;
    s0s[(pb)     * 33 + c] = a0;
    s0s[(pb + 1) * 33 + c] = a1;
    s0s[(pb + 2) * 33 + c] = a2;
    s0s[(pb + 3) * 33 + c] = a3;
  }
  __syncthreads();

  // ---- P2: k dwconv -> register; v dwconv (p2 from p1s max4) -> vsh ----
  int ebT = t >> 5, jT = t & 31;
  float kreg;
  {
    const float* wc = w1 + jT * 9;
    const float* Pk = p1s + jT * 73 + ((th & 1) + 1) * 12 + ebT + 1;
    float acc = b1[jT];
    acc = fmaf(wc[0], Pk[0],  fmaf(wc[1], Pk[1],  fmaf(wc[2], Pk[2],  acc)));
    acc = fmaf(wc[3], Pk[12], fmaf(wc[4], Pk[13], fmaf(wc[5], Pk[14], acc)));
    acc = fmaf(wc[6], Pk[24], fmaf(wc[7], Pk[25], fmaf(wc[8], Pk[26], acc)));
    kreg = acc;
  }
  {
    const float* wc = w2 + jT * 9;
    const float* P = p1s + jT * 73;
    int cb0 = 2 * (ebT >> 1);
    float acc = b2[jT];
#pragma unroll
    for (int hq = 0; hq < 3; ++hq) {
      const float* Pr = P + 2 * hq * 12;
#pragma unroll
      for (int wq = 0; wq < 3; ++wq) {
        int cb = cb0 + 2 * wq;
        float p2v = fmaxf(fmaxf(Pr[cb], Pr[cb + 1]), fmaxf(Pr[cb + 12], Pr[cb + 13]));
        acc = fmaf(wc[hq * 3 + wq], p2v, acc);
      }
    }
    vsh[ebT * 36 + jT] = acc;
  }
  __syncthreads();

  // ---- P3: E column j of block eb (unscaled), streamed fp16 pack ----
  {
    const float* vb = vsh + ebT * 36;
    const float4* v4 = (const float4*)vb;
    float4 q0 = v4[0];
    float vmax = fmaxf(fmaxf(q0.x, q0.y), fmaxf(q0.z, q0.w));
    float vmin = fminf(fminf(q0.x, q0.y), fminf(q0.z, q0.w));
#pragma unroll
    for (int iq = 1; iq < 8; ++iq) {
      float4 q_ = v4[iq];
      vmax = fmaxf(vmax, fmaxf(fmaxf(q_.x, q_.y), fmaxf(q_.z, q_.w)));
      vmin = fminf(vmin, fminf(fminf(q_.x, q_.y), fminf(q_.z, q_.w)));
    }
    const float L2E = 1.4426950408889634f;
    float m  = (kreg >= 0.f) ? kreg * vmax : kreg * vmin;
    float kl = kreg * L2E;
    float nm = -m * L2E;
    float d0 = 0.f, d1 = 0.f;
    unsigned int* EB = regA + ebT * 516 + jT;
#pragma unroll
    for (int ip = 0; ip < 16; ++ip) {
      float2 vp = *(const float2*)(vb + 2 * ip);
      float e0 = __builtin_amdgcn_exp2f(fmaf(vp.x, kl, nm));
      float e1 = __builtin_amdgcn_exp2f(fmaf(vp.y, kl, nm));
      d0 += e0; d1 += e1;
      EB[ip * 32] = f2h2(e0, e1);
    }
    rds[ebT * 33 + jT] = __fdividef(1.f, d0 + d1);
  }
  __syncthreads();

  // ---- P4: qkv[i] = sum_j E[i,j] * (q[p,j] * rd[j]) ----
  {
    int p = t & 31, ic = t >> 5;               // pixel p, i-chunk ic (4 i's)
    int eb = (p & 15) >> 1;
    const unsigned int* EB = regA + eb * 516;
    const float* qrow = s0s + p * 33;
    const float* rdr = rds + eb * 33;
    float a0 = 0.f, a1 = 0.f, a2 = 0.f, a3 = 0.f;
#pragma unroll
    for (int jw = 0; jw < 8; ++jw) {
      uint4 wA = *(const uint4*)(EB + (2 * ic)     * 32 + jw * 4);
      uint4 wB = *(const uint4*)(EB + (2 * ic + 1) * 32 + jw * 4);
      float q0 = qrow[4 * jw]     * rdr[4 * jw];
      float q1 = qrow[4 * jw + 1] * rdr[4 * jw + 1];
      float q2 = qrow[4 * jw + 2] * rdr[4 * jw + 2];
      float q3 = qrow[4 * jw + 3] * rdr[4 * jw + 3];
      float2 f;
      f = h2f2(wA.x); a0 = fmaf(f.x, q0, a0); a1 = fmaf(f.y, q0, a1);
      f = h2f2(wA.y); a0 = fmaf(f.x, q1, a0); a1 = fmaf(f.y, q1, a1);
      f = h2f2(wA.z); a0 = fmaf(f.x, q2, a0); a1 = fmaf(f.y, q2, a1);
      f = h2f2(wA.w); a0 = fmaf(f.x, q3, a0); a1 = fmaf(f.y, q3, a1);
      f = h2f2(wB.x); a2 = fmaf(f.x, q0, a2); a3 = fmaf(f.y, q0, a3);
      f = h2f2(wB.y); a2 = fmaf(f.x, q1, a2); a3 = fmaf(f.y, q1, a3);
      f = h2f2(wB.z); a2 = fmaf(f.x, q2, a2); a3 = fmaf(f.y, q2, a3);
      f = h2f2(wB.w); a2 = fmaf(f.x, q3, a2); a3 = fmaf(f.y, q3, a3);
    }
    float* qd = qkvs + p * 33 + ic * 4;
    qd[0] = a0; qd[1] = a1; qd[2] = a2; qd[3] = a3;
  }
  __syncthreads();

  // ---- P5: 1x1 conv (wa from global, L1 broadcast) + GELU + mul x ----
  {
    int o = t >> 3, g = t & 7;
    int hh = g >> 2, wb = (g & 3) * 4;
    const float* wo = wa + o * 32;
    const float* q0 = qkvs + (hh * 16 + wb)     * 33;
    const float* q1 = qkvs + (hh * 16 + wb + 1) * 33;
    const float* q2 = qkvs + (hh * 16 + wb + 2) * 33;
    const float* q3 = qkvs + (hh * 16 + wb + 3) * 33;
    float bz = ba[o];
    float y0 = bz, y1 = bz, y2 = bz, y3 = bz;
#pragma unroll
    for (int i = 0; i < 32; ++i) {
      float w = wo[i];
      y0 = fmaf(w, q0[i], y0);
      y1 = fmaf(w, q1[i], y1);
      y2 = fmaf(w, q2[i], y2);
      y3 = fmaf(w, q3[i], y3);
    }
    const float RS2 = 0.70710678118654752f;
    float g0 = 0.5f * y0 * (1.f + erff(y0 * RS2));
    float g1 = 0.5f * y1 * (1.f + erff(y1 * RS2));
    float g2 = 0.5f * y2 * (1.f + erff(y2 * RS2));
    float g3 = 0.5f * y3 * (1.f + erff(y3 * RS2));
    size_t ob = (((size_t)(b * 32 + o) * 128) + (2 * th + hh)) * 128 + 16 * tw + wb;
    float4 xv = *(const float4*)(x + ob);
    float4 r;
    r.x = g0 * xv.x; r.y = g1 * xv.y; r.z = g2 * xv.z; r.w = g3 * xv.w;
    *(float4*)(out + ob) = r;
  }
}

// ---------------------------------------------------------------------------
extern "C" void kernel_launch(void* const* d_in, const int* in_sizes, int n_in,
                              void* d_out, int out_size, void* d_ws, size_t ws_size,
                              hipStream_t stream) {
  const float* x  = (const float*)d_in[0];
  const float* w0 = (const float*)d_in[1];
  const float* b0 = (const float*)d_in[2];
  const float* w1 = (const float*)d_in[3];
  const float* b1 = (const float*)d_in[4];
  const float* w2 = (const float*)d_in[5];
  const float* b2 = (const float*)d_in[6];
  const float* wa = (const float*)d_in[7];
  const float* ba = (const float*)d_in[8];
  float* out = (float*)d_out;

  fused_safm<<<2048, 256, 0, stream>>>(x, w0, b0, w1, b1, w2, b2, wa, ba, out);
}

// Round 10
// 105.545 us; speedup vs baseline: 1.3733x; 1.0097x over previous
//
#include <hip/hip_runtime.h>
#include <hip/hip_fp16.h>
#include <math.h>

// ---------------------------------------------------------------------------
// Fully-fused SAFM, one launch. Tile = 16w x 2h pixels, grid 2048 = 4b*64th*8tw.
// Each 2x2 pixel block (eb 0..7) shares one k (half-res) and one v (quarter-res)
// pixel => one E[i][j] = exp(v_i k_j)/denom_j matrix per eb.
//
// R10 = R9 with the qkvs swizzle overlap bug fixed:
//   R9's QS(p)=p*36+((p&3)<<2) let rows extend to p*36+43 > next row start
//   (p*36+36) -> P4 cross-pixel overwrite, P5 cross-pixel reads (absmax 4.39).
//   Now stride 64, QS(p)=p*64+(((p>>2)&7)<<2): extent 59 < 64 (no overlap);
//   P5's 8 lane-rows start at banks {0,4,...,28} -> b128 reads conflict-free.
// ---------------------------------------------------------------------------

typedef _Float16 half2_t __attribute__((ext_vector_type(2)));

__device__ __forceinline__ half2_t bch2(unsigned int u) {
  return __builtin_bit_cast(half2_t, u);
}
__device__ __forceinline__ float fdot2(unsigned int a, unsigned int b, float c) {
  return __builtin_amdgcn_fdot2(bch2(a), bch2(b), c, false);
}

// qkvs addressing: stride 64 + quad-rotation; extent <= 59 so rows never overlap
__device__ __forceinline__ int QS(int p) { return p * 64 + (((p >> 2) & 7) << 2); }

__global__ __launch_bounds__(256) void fused_safm(
    const float* __restrict__ x,
    const float* __restrict__ w0, const float* __restrict__ b0,
    const float* __restrict__ w1, const float* __restrict__ b1,
    const float* __restrict__ w2, const float* __restrict__ b2,
    const float* __restrict__ wa, const float* __restrict__ ba,
    float* __restrict__ out) {
  int bid = blockIdx.x;
  int tw = bid & 7, th = (bid >> 3) & 63, b = bid >> 9;
  int t = threadIdx.x;
  int h4 = th >> 1;

  // E fp16: half-index = eb*1032 + i*32 + j  (word = eb*516 + i*16 + j/2)
  // eb word-stride 516 -> 8 ebs start 4 banks apart (2-way on b128 reads = free)
  __shared__ __align__(16) unsigned int regA[4128];   // 16.5 KB; overlays p1s
  __shared__ __align__(16) unsigned int qrdsh[544];   // q*rd fp16: eb*136+px*32+j (halves)
  __shared__ __align__(16) float s0s[1056];           // [p][c] stride 33
  __shared__ __align__(16) float vsh[288];            // [eb][i] stride 36
  __shared__ __align__(16) float qkvs[2048];          // QS(p)+i, f32, stride 64
  float* p1s = (float*)regA;                          // [c][6r][12w] c-stride 76

  // ---- P1a: pool p1 tile (rows 2h4-2..+3, cols 8tw-2..+9), 4 cells/unit ----
  {
    const float* xb = x + ((size_t)(b * 32) << 14);
#pragma unroll
    for (int k = 0; k < 3; ++k) {
      int idx = t + k * 256;                  // 576 units = 32c * 6r * 3seg
      if (idx < 576) {
        int c = idx / 18, rem = idx % 18;
        int r = rem / 3, s = rem % 3;
        int pr = 2 * h4 - 2 + r;
        int pc0 = 8 * tw - 2 + 4 * s;
        float m0 = 0.f, m1 = 0.f, m2 = 0.f, m3 = 0.f;
        if ((unsigned)pr < 64u) {
          const float* xp = xb + ((size_t)c << 14) + (2 * pr) * 128;
          if (pc0 >= 0 && pc0 + 3 < 64) {     // interior fast path
            const float* q = xp + 2 * pc0;
            float4 a0 = *(const float4*)q;
            float4 a1 = *(const float4*)(q + 4);
            float4 c0 = *(const float4*)(q + 128);
            float4 c1 = *(const float4*)(q + 132);
            m0 = fmaxf(fmaxf(a0.x, a0.y), fmaxf(c0.x, c0.y));
            m1 = fmaxf(fmaxf(a0.z, a0.w), fmaxf(c0.z, c0.w));
            m2 = fmaxf(fmaxf(a1.x, a1.y), fmaxf(c1.x, c1.y));
            m3 = fmaxf(fmaxf(a1.z, a1.w), fmaxf(c1.z, c1.w));
          } else {                            // edge slow path
            float mm[4] = {0.f, 0.f, 0.f, 0.f};
#pragma unroll
            for (int m_ = 0; m_ < 4; ++m_) {
              int pc = pc0 + m_;
              if ((unsigned)pc < 64u) {
                const float* q = xp + 2 * pc;
                float2 r0 = *(const float2*)q;
                float2 r1 = *(const float2*)(q + 128);
                mm[m_] = fmaxf(fmaxf(r0.x, r0.y), fmaxf(r1.x, r1.y));
              }
            }
            m0 = mm[0]; m1 = mm[1]; m2 = mm[2]; m3 = mm[3];
          }
        }
        *(float4*)(p1s + c * 76 + r * 12 + 4 * s) = make_float4(m0, m1, m2, m3);
      }
    }
  }
  // ---- P1b: s0 dwconv (full res) from global -> s0s (pixel-major) ----
  {
    int c = t >> 3, gg = t & 7;
    int hh = gg >> 2, wb = (gg & 3) * 4;
    const float* xp = x + ((size_t)(b * 32 + c) << 14);
    const float* wc = w0 + c * 9;
    float wv[9];
#pragma unroll
    for (int q = 0; q < 9; ++q) wv[q] = wc[q];
    float bz = b0[c];
    float a0 = bz, a1 = bz, a2 = bz, a3 = bz;
    int cbase = 16 * tw + wb;
#pragma unroll
    for (int dr = -1; dr <= 1; ++dr) {
      int row = 2 * th + hh + dr;
      if ((unsigned)row >= 128u) continue;
      const float* rp = xp + row * 128 + cbase;
      float cm1 = (cbase > 0)       ? rp[-1] : 0.f;
      float4 c03 = *(const float4*)rp;
      float c4  = (cbase + 4 < 128) ? rp[4]  : 0.f;
      float wA = wv[(dr + 1) * 3], wB = wv[(dr + 1) * 3 + 1], wC = wv[(dr + 1) * 3 + 2];
      a0 = fmaf(wA, cm1,   fmaf(wB, c03.x, fmaf(wC, c03.y, a0)));
      a1 = fmaf(wA, c03.x, fmaf(wB, c03.y, fmaf(wC, c03.z, a1)));
      a2 = fmaf(wA, c03.y, fmaf(wB, c03.z, fmaf(wC, c03.w, a2)));
      a3 = fmaf(wA, c03.z, fmaf(wB, c03.w, fmaf(wC, c4,    a3)));
    }
    int pb = hh * 16 + wb;
    s0s[(pb)     * 33 + c] = a0;
    s0s[(pb + 1) * 33 + c] = a1;
    s0s[(pb + 2) * 33 + c] = a2;
    s0s[(pb + 3) * 33 + c] = a3;
  }
  __syncthreads();

  // ---- P2: k dwconv -> register; v dwconv (p2 = max4(p1s) on the fly) ----
  int ebT = t >> 5, jT = t & 31;
  float kreg;
  {
    const float* wc = w1 + jT * 9;
    const float* Pk = p1s + jT * 76 + ((th & 1) + 1) * 12 + ebT + 1;
    float acc = b1[jT];
    acc = fmaf(wc[0], Pk[0],  fmaf(wc[1], Pk[1],  fmaf(wc[2], Pk[2],  acc)));
    acc = fmaf(wc[3], Pk[12], fmaf(wc[4], Pk[13], fmaf(wc[5], Pk[14], acc)));
    acc = fmaf(wc[6], Pk[24], fmaf(wc[7], Pk[25], fmaf(wc[8], Pk[26], acc)));
    kreg = acc;
  }
  {
    const float* wc = w2 + jT * 9;
    const float* P = p1s + jT * 76 + 2 * (ebT >> 1);
    float acc = b2[jT];
#pragma unroll
    for (int hq = 0; hq < 3; ++hq) {
      const float* Pr = P + 2 * hq * 12;
#pragma unroll
      for (int wq = 0; wq < 3; ++wq) {
        float2 u0 = *(const float2*)(Pr + 2 * wq);
        float2 u1 = *(const float2*)(Pr + 2 * wq + 12);
        float p2v = fmaxf(fmaxf(u0.x, u0.y), fmaxf(u1.x, u1.y));
        acc = fmaf(wc[hq * 3 + wq], p2v, acc);
      }
    }
    vsh[ebT * 36 + jT] = acc;
  }
  __syncthreads();

  // ---- P3: E column j (unscaled, fp16, paired-along-j layout); q*rd tail ----
  {
    const float* vb = vsh + ebT * 36;
    const float4* v4 = (const float4*)vb;
    float4 q0 = v4[0];
    float vmax = fmaxf(fmaxf(q0.x, q0.y), fmaxf(q0.z, q0.w));
    float vmin = fminf(fminf(q0.x, q0.y), fminf(q0.z, q0.w));
#pragma unroll
    for (int iq = 1; iq < 8; ++iq) {
      float4 q_ = v4[iq];
      vmax = fmaxf(vmax, fmaxf(fmaxf(q_.x, q_.y), fmaxf(q_.z, q_.w)));
      vmin = fminf(vmin, fminf(fminf(q_.x, q_.y), fminf(q_.z, q_.w)));
    }
    const float L2E = 1.4426950408889634f;
    float m  = (kreg >= 0.f) ? kreg * vmax : kreg * vmin;
    float kl = kreg * L2E;
    float nm = -m * L2E;
    float d0 = 0.f, d1 = 0.f;
    __half* Eh = (__half*)regA;
    int colbase = ebT * 1032 + jT;            // + i*32 per row
#pragma unroll
    for (int ip = 0; ip < 16; ++ip) {
      float2 vp = *(const float2*)(vb + 2 * ip);
      float e0 = __builtin_amdgcn_exp2f(fmaf(vp.x, kl, nm));
      float e1 = __builtin_amdgcn_exp2f(fmaf(vp.y, kl, nm));
      d0 += e0; d1 += e1;
      Eh[colbase + (2 * ip) * 32]     = __float2half(e0);
      Eh[colbase + (2 * ip + 1) * 32] = __float2half(e1);
    }
    float rd = __fdividef(1.f, d0 + d1);
    __half* Qh = (__half*)qrdsh;
    int qbase = ebT * 136 + jT;               // + px*32 per pixel
#pragma unroll
    for (int px = 0; px < 4; ++px) {
      int hh = px >> 1, wwb = px & 1;
      int p = hh * 16 + ebT * 2 + wwb;
      float qv = s0s[p * 33 + jT] * rd;
      Qh[qbase + px * 32] = __float2half(qv);
    }
  }
  __syncthreads();

  // ---- P4: qkv[i] = sum_j E[i,j]*(q rd)[j] via v_dot2_f32_f16 ----
  {
    int p = t & 31, ic = t >> 5;              // pixel p, i-chunk ic (4 i's)
    int eb = (p & 15) >> 1;
    int px = 2 * (p >> 4) + (p & 1);
    const uint4* Eq = (const uint4*)(regA + eb * 516);      // quad idx = i*4+k
    const uint4* Uq = (const uint4*)(qrdsh + eb * 68 + px * 16);
    uint4 u0 = Uq[0], u1 = Uq[1], u2 = Uq[2], u3 = Uq[3];
    float a0, a1, a2, a3;
#define SAFM_ROW(di, dst)                                              \
    {                                                                  \
      const uint4* Er = Eq + (4 * ic + di) * 4;                        \
      uint4 w0_ = Er[0], w1_ = Er[1], w2_ = Er[2], w3_ = Er[3];        \
      float s_ = 0.f;                                                  \
      s_ = fdot2(w0_.x, u0.x, s_); s_ = fdot2(w0_.y, u0.y, s_);        \
      s_ = fdot2(w0_.z, u0.z, s_); s_ = fdot2(w0_.w, u0.w, s_);        \
      s_ = fdot2(w1_.x, u1.x, s_); s_ = fdot2(w1_.y, u1.y, s_);        \
      s_ = fdot2(w1_.z, u1.z, s_); s_ = fdot2(w1_.w, u1.w, s_);        \
      s_ = fdot2(w2_.x, u2.x, s_); s_ = fdot2(w2_.y, u2.y, s_);        \
      s_ = fdot2(w2_.z, u2.z, s_); s_ = fdot2(w2_.w, u2.w, s_);        \
      s_ = fdot2(w3_.x, u3.x, s_); s_ = fdot2(w3_.y, u3.y, s_);        \
      s_ = fdot2(w3_.z, u3.z, s_); s_ = fdot2(w3_.w, u3.w, s_);        \
      dst = s_;                                                        \
    }
    SAFM_ROW(0, a0) SAFM_ROW(1, a1) SAFM_ROW(2, a2) SAFM_ROW(3, a3)
#undef SAFM_ROW
    *(float4*)(qkvs + QS(p) + 4 * ic) = make_float4(a0, a1, a2, a3);
  }
  __syncthreads();

  // ---- P5: 1x1 conv (wa global, reg-reused x4) + exact GELU + mul x ----
  {
    int o = t >> 3, g = t & 7;
    int hh = g >> 2, wb = (g & 3) * 4;
    const float* wo = wa + o * 32;
    const float* qA = qkvs + QS(hh * 16 + wb);
    const float* qB = qkvs + QS(hh * 16 + wb + 1);
    const float* qC = qkvs + QS(hh * 16 + wb + 2);
    const float* qD = qkvs + QS(hh * 16 + wb + 3);
    float bz = ba[o];
    float y0 = bz, y1 = bz, y2 = bz, y3 = bz;
#pragma unroll
    for (int m = 0; m < 8; ++m) {
      float4 fA = *(const float4*)(qA + 4 * m);
      float4 fB = *(const float4*)(qB + 4 * m);
      float4 fC = *(const float4*)(qC + 4 * m);
      float4 fD = *(const float4*)(qD + 4 * m);
      float wv0 = wo[4 * m], wv1 = wo[4 * m + 1], wv2 = wo[4 * m + 2], wv3 = wo[4 * m + 3];
      y0 = fmaf(wv0, fA.x, fmaf(wv1, fA.y, fmaf(wv2, fA.z, fmaf(wv3, fA.w, y0))));
      y1 = fmaf(wv0, fB.x, fmaf(wv1, fB.y, fmaf(wv2, fB.z, fmaf(wv3, fB.w, y1))));
      y2 = fmaf(wv0, fC.x, fmaf(wv1, fC.y, fmaf(wv2, fC.z, fmaf(wv3, fC.w, y2))));
      y3 = fmaf(wv0, fD.x, fmaf(wv1, fD.y, fmaf(wv2, fD.z, fmaf(wv3, fD.w, y3))));
    }
    const float RS2 = 0.70710678118654752f;
    float g0 = 0.5f * y0 * (1.f + erff(y0 * RS2));
    float g1 = 0.5f * y1 * (1.f + erff(y1 * RS2));
    float g2 = 0.5f * y2 * (1.f + erff(y2 * RS2));
    float g3 = 0.5f * y3 * (1.f + erff(y3 * RS2));
    size_t ob = (((size_t)(b * 32 + o) * 128) + (2 * th + hh)) * 128 + 16 * tw + wb;
    float4 xv = *(const float4*)(x + ob);
    float4 r;
    r.x = g0 * xv.x; r.y = g1 * xv.y; r.z = g2 * xv.z; r.w = g3 * xv.w;
    *(float4*)(out + ob) = r;
  }
}

// ---------------------------------------------------------------------------
extern "C" void kernel_launch(void* const* d_in, const int* in_sizes, int n_in,
                              void* d_out, int out_size, void* d_ws, size_t ws_size,
                              hipStream_t stream) {
  const float* x  = (const float*)d_in[0];
  const float* w0 = (const float*)d_in[1];
  const float* b0 = (const float*)d_in[2];
  const float* w1 = (const float*)d_in[3];
  const float* b1 = (const float*)d_in[4];
  const float* w2 = (const float*)d_in[5];
  const float* b2 = (const float*)d_in[6];
  const float* wa = (const float*)d_in[7];
  const float* ba = (const float*)d_in[8];
  float* out = (float*)d_out;

  fused_safm<<<2048, 256, 0, stream>>>(x, w0, b0, w1, b1, w2, b2, wa, ba, out);
}

// Round 11
// 102.939 us; speedup vs baseline: 1.4081x; 1.0253x over previous
//
#include <hip/hip_runtime.h>
#include <math.h>

// ---------------------------------------------------------------------------
// Fully-fused SAFM, one launch. Tile = 16w x 2h pixels, grid 2048 = 4b*64th*8tw.
// Each 2x2 pixel block (eb 0..7) shares one k (half-res) and one v (quarter-res)
// pixel => one E[i][j] = exp(v_i k_j)/denom_j matrix per eb.
//
// R11: E is NEVER MATERIALIZED (R8-R10 showed the fp16-E LDS round trip +
// capacity was the structural cost). Column pass computes denominators and
// stores only (kl_j, nm_j) + q*rd (6 KB); row pass RECOMPUTES the exps and
// accumulates qkv directly. Exps double (trans pipe, cheap); deleted: E
// stores/loads, fp16 cvts (full f32 accuracy back), 16.5 KB LDS.
// LDS 21.25 KB -> 7 blocks/CU static. No launch_bounds min-waves (R5/R6:
// it forces spills).
// ---------------------------------------------------------------------------

// qkvs addressing: stride 64 + quad-rotation; extent <= 59 so rows never overlap
__device__ __forceinline__ int QS(int p) { return p * 64 + (((p >> 2) & 7) << 2); }

__global__ __launch_bounds__(256) void fused_safm(
    const float* __restrict__ x,
    const float* __restrict__ w0, const float* __restrict__ b0,
    const float* __restrict__ w1, const float* __restrict__ b1,
    const float* __restrict__ w2, const float* __restrict__ b2,
    const float* __restrict__ wa, const float* __restrict__ ba,
    float* __restrict__ out) {
  int bid = blockIdx.x;
  int tw = bid & 7, th = (bid >> 3) & 63, b = bid >> 9;
  int t = threadIdx.x;
  int h4 = th >> 1;

  __shared__ __align__(16) float regAB[2432];  // p1s (P1-P2) / qkvs (P4-P5) overlay
  __shared__ __align__(16) float klns[512];    // (eb*32+j)*2: {kl_j, nm_j}
  __shared__ __align__(16) float qds[1024];    // (eb*32+j)*4: q[px]*rd
  __shared__ __align__(16) float s0s[1056];    // [p][c] stride 33
  __shared__ __align__(16) float vsh[288];     // [eb][i] stride 36
  float* p1s  = regAB;                         // [c][6r][12w] c-stride 76
  float* qkvs = regAB;                         // QS(p)+i, stride 64

  // ---- P1a: pool p1 tile (rows 2h4-2..+3, cols 8tw-2..+9), 4 cells/unit ----
  {
    const float* xb = x + ((size_t)(b * 32) << 14);
#pragma unroll
    for (int k = 0; k < 3; ++k) {
      int idx = t + k * 256;                  // 576 units = 32c * 6r * 3seg
      if (idx < 576) {
        int c = idx / 18, rem = idx % 18;
        int r = rem / 3, s = rem % 3;
        int pr = 2 * h4 - 2 + r;
        int pc0 = 8 * tw - 2 + 4 * s;
        float m0 = 0.f, m1 = 0.f, m2 = 0.f, m3 = 0.f;
        if ((unsigned)pr < 64u) {
          const float* xp = xb + ((size_t)c << 14) + (2 * pr) * 128;
          if (pc0 >= 0 && pc0 + 3 < 64) {     // interior fast path
            const float* q = xp + 2 * pc0;
            float4 a0 = *(const float4*)q;
            float4 a1 = *(const float4*)(q + 4);
            float4 c0 = *(const float4*)(q + 128);
            float4 c1 = *(const float4*)(q + 132);
            m0 = fmaxf(fmaxf(a0.x, a0.y), fmaxf(c0.x, c0.y));
            m1 = fmaxf(fmaxf(a0.z, a0.w), fmaxf(c0.z, c0.w));
            m2 = fmaxf(fmaxf(a1.x, a1.y), fmaxf(c1.x, c1.y));
            m3 = fmaxf(fmaxf(a1.z, a1.w), fmaxf(c1.z, c1.w));
          } else {                            // edge slow path
            float mm[4] = {0.f, 0.f, 0.f, 0.f};
#pragma unroll
            for (int m_ = 0; m_ < 4; ++m_) {
              int pc = pc0 + m_;
              if ((unsigned)pc < 64u) {
                const float* q = xp + 2 * pc;
                float2 r0 = *(const float2*)q;
                float2 r1 = *(const float2*)(q + 128);
                mm[m_] = fmaxf(fmaxf(r0.x, r0.y), fmaxf(r1.x, r1.y));
              }
            }
            m0 = mm[0]; m1 = mm[1]; m2 = mm[2]; m3 = mm[3];
          }
        }
        *(float4*)(p1s + c * 76 + r * 12 + 4 * s) = make_float4(m0, m1, m2, m3);
      }
    }
  }
  // ---- P1b: s0 dwconv (full res) from global -> s0s (pixel-major) ----
  {
    int c = t >> 3, gg = t & 7;
    int hh = gg >> 2, wb = (gg & 3) * 4;
    const float* xp = x + ((size_t)(b * 32 + c) << 14);
    const float* wc = w0 + c * 9;
    float wv[9];
#pragma unroll
    for (int q = 0; q < 9; ++q) wv[q] = wc[q];
    float bz = b0[c];
    float a0 = bz, a1 = bz, a2 = bz, a3 = bz;
    int cbase = 16 * tw + wb;
#pragma unroll
    for (int dr = -1; dr <= 1; ++dr) {
      int row = 2 * th + hh + dr;
      if ((unsigned)row >= 128u) continue;
      const float* rp = xp + row * 128 + cbase;
      float cm1 = (cbase > 0)       ? rp[-1] : 0.f;
      float4 c03 = *(const float4*)rp;
      float c4  = (cbase + 4 < 128) ? rp[4]  : 0.f;
      float wA = wv[(dr + 1) * 3], wB = wv[(dr + 1) * 3 + 1], wC = wv[(dr + 1) * 3 + 2];
      a0 = fmaf(wA, cm1,   fmaf(wB, c03.x, fmaf(wC, c03.y, a0)));
      a1 = fmaf(wA, c03.x, fmaf(wB, c03.y, fmaf(wC, c03.z, a1)));
      a2 = fmaf(wA, c03.y, fmaf(wB, c03.z, fmaf(wC, c03.w, a2)));
      a3 = fmaf(wA, c03.z, fmaf(wB, c03.w, fmaf(wC, c4,    a3)));
    }
    int pb = hh * 16 + wb;
    s0s[(pb)     * 33 + c] = a0;
    s0s[(pb + 1) * 33 + c] = a1;
    s0s[(pb + 2) * 33 + c] = a2;
    s0s[(pb + 3) * 33 + c] = a3;
  }
  __syncthreads();

  // ---- P2: k dwconv -> register; v dwconv (p2 = max4(p1s) on the fly) ----
  int ebT = t >> 5, jT = t & 31;
  float kreg;
  {
    const float* wc = w1 + jT * 9;
    const float* Pk = p1s + jT * 76 + ((th & 1) + 1) * 12 + ebT + 1;
    float acc = b1[jT];
    acc = fmaf(wc[0], Pk[0],  fmaf(wc[1], Pk[1],  fmaf(wc[2], Pk[2],  acc)));
    acc = fmaf(wc[3], Pk[12], fmaf(wc[4], Pk[13], fmaf(wc[5], Pk[14], acc)));
    acc = fmaf(wc[6], Pk[24], fmaf(wc[7], Pk[25], fmaf(wc[8], Pk[26], acc)));
    kreg = acc;
  }
  {
    const float* wc = w2 + jT * 9;
    const float* P = p1s + jT * 76 + 2 * (ebT >> 1);
    float acc = b2[jT];
#pragma unroll
    for (int hq = 0; hq < 3; ++hq) {
      const float* Pr = P + 2 * hq * 12;
#pragma unroll
      for (int wq = 0; wq < 3; ++wq) {
        float2 u0 = *(const float2*)(Pr + 2 * wq);
        float2 u1 = *(const float2*)(Pr + 2 * wq + 12);
        float p2v = fmaxf(fmaxf(u0.x, u0.y), fmaxf(u1.x, u1.y));
        acc = fmaf(wc[hq * 3 + wq], p2v, acc);
      }
    }
    vsh[ebT * 36 + jT] = acc;
  }
  __syncthreads();

  // ---- P3 (column pass): denom_j; store {kl_j, nm_j} and q[px]*rd only ----
  {
    const float* vb = vsh + ebT * 36;
    const float4* v4 = (const float4*)vb;
    float4 q0 = v4[0];
    float vmax = fmaxf(fmaxf(q0.x, q0.y), fmaxf(q0.z, q0.w));
    float vmin = fminf(fminf(q0.x, q0.y), fminf(q0.z, q0.w));
#pragma unroll
    for (int iq = 1; iq < 8; ++iq) {
      float4 q_ = v4[iq];
      vmax = fmaxf(vmax, fmaxf(fmaxf(q_.x, q_.y), fmaxf(q_.z, q_.w)));
      vmin = fminf(vmin, fminf(fminf(q_.x, q_.y), fminf(q_.z, q_.w)));
    }
    const float L2E = 1.4426950408889634f;
    float m  = (kreg >= 0.f) ? kreg * vmax : kreg * vmin;   // max_i v_i*k_j
    float kl = kreg * L2E;
    float nm = -m * L2E;
    float d0 = 0.f, d1 = 0.f;
#pragma unroll
    for (int ip = 0; ip < 16; ++ip) {
      float2 vp = *(const float2*)(vb + 2 * ip);
      d0 += __builtin_amdgcn_exp2f(fmaf(vp.x, kl, nm));
      d1 += __builtin_amdgcn_exp2f(fmaf(vp.y, kl, nm));
    }
    float rd = __fdividef(1.f, d0 + d1);
    *(float2*)(klns + (ebT * 32 + jT) * 2) = make_float2(kl, nm);
    float4 qv;                                  // px = (hh,wwb): p = hh*16+eb*2+wwb
    qv.x = s0s[(ebT * 2)      * 33 + jT] * rd;
    qv.y = s0s[(ebT * 2 + 1)  * 33 + jT] * rd;
    qv.z = s0s[(ebT * 2 + 16) * 33 + jT] * rd;
    qv.w = s0s[(ebT * 2 + 17) * 33 + jT] * rd;
    *(float4*)(qds + (ebT * 32 + jT) * 4) = qv;
  }
  __syncthreads();

  // ---- P4 (row pass): qkv[i][px] = sum_j exp(v_i*kl_j+nm_j) * qd[j][px] ----
  {
    int i = t & 31, eb = t >> 5;
    float vi = vsh[eb * 36 + i];
    const float* klp = klns + eb * 64;
    const float* qdp = qds + eb * 128;
    float a0 = 0.f, a1 = 0.f, a2 = 0.f, a3 = 0.f;
#pragma unroll
    for (int jw = 0; jw < 8; ++jw) {
      float4 k01 = *(const float4*)(klp + jw * 8);       // {kl,nm}x2 (broadcast)
      float4 k23 = *(const float4*)(klp + jw * 8 + 4);
      float4 qd0 = *(const float4*)(qdp + jw * 16);
      float4 qd1 = *(const float4*)(qdp + jw * 16 + 4);
      float4 qd2 = *(const float4*)(qdp + jw * 16 + 8);
      float4 qd3 = *(const float4*)(qdp + jw * 16 + 12);
      float e;
      e = __builtin_amdgcn_exp2f(fmaf(vi, k01.x, k01.y));
      a0 = fmaf(e, qd0.x, a0); a1 = fmaf(e, qd0.y, a1);
      a2 = fmaf(e, qd0.z, a2); a3 = fmaf(e, qd0.w, a3);
      e = __builtin_amdgcn_exp2f(fmaf(vi, k01.z, k01.w));
      a0 = fmaf(e, qd1.x, a0); a1 = fmaf(e, qd1.y, a1);
      a2 = fmaf(e, qd1.z, a2); a3 = fmaf(e, qd1.w, a3);
      e = __builtin_amdgcn_exp2f(fmaf(vi, k23.x, k23.y));
      a0 = fmaf(e, qd2.x, a0); a1 = fmaf(e, qd2.y, a1);
      a2 = fmaf(e, qd2.z, a2); a3 = fmaf(e, qd2.w, a3);
      e = __builtin_amdgcn_exp2f(fmaf(vi, k23.z, k23.w));
      a0 = fmaf(e, qd3.x, a0); a1 = fmaf(e, qd3.y, a1);
      a2 = fmaf(e, qd3.z, a2); a3 = fmaf(e, qd3.w, a3);
    }
    int p0 = eb * 2;
    qkvs[QS(p0)      + i] = a0;
    qkvs[QS(p0 + 1)  + i] = a1;
    qkvs[QS(p0 + 16) + i] = a2;
    qkvs[QS(p0 + 17) + i] = a3;
  }
  __syncthreads();

  // ---- P5: 1x1 conv (wa global, reg-reused x4) + exact GELU + mul x ----
  {
    int o = t >> 3, g = t & 7;
    int hh = g >> 2, wb = (g & 3) * 4;
    const float* wo = wa + o * 32;
    const float* qA = qkvs + QS(hh * 16 + wb);
    const float* qB = qkvs + QS(hh * 16 + wb + 1);
    const float* qC = qkvs + QS(hh * 16 + wb + 2);
    const float* qD = qkvs + QS(hh * 16 + wb + 3);
    float bz = ba[o];
    float y0 = bz, y1 = bz, y2 = bz, y3 = bz;
#pragma unroll
    for (int m = 0; m < 8; ++m) {
      float4 fA = *(const float4*)(qA + 4 * m);
      float4 fB = *(const float4*)(qB + 4 * m);
      float4 fC = *(const float4*)(qC + 4 * m);
      float4 fD = *(const float4*)(qD + 4 * m);
      float wv0 = wo[4 * m], wv1 = wo[4 * m + 1], wv2 = wo[4 * m + 2], wv3 = wo[4 * m + 3];
      y0 = fmaf(wv0, fA.x, fmaf(wv1, fA.y, fmaf(wv2, fA.z, fmaf(wv3, fA.w, y0))));
      y1 = fmaf(wv0, fB.x, fmaf(wv1, fB.y, fmaf(wv2, fB.z, fmaf(wv3, fB.w, y1))));
      y2 = fmaf(wv0, fC.x, fmaf(wv1, fC.y, fmaf(wv2, fC.z, fmaf(wv3, fC.w, y2))));
      y3 = fmaf(wv0, fD.x, fmaf(wv1, fD.y, fmaf(wv2, fD.z, fmaf(wv3, fD.w, y3))));
    }
    const float RS2 = 0.70710678118654752f;
    float g0 = 0.5f * y0 * (1.f + erff(y0 * RS2));
    float g1 = 0.5f * y1 * (1.f + erff(y1 * RS2));
    float g2 = 0.5f * y2 * (1.f + erff(y2 * RS2));
    float g3 = 0.5f * y3 * (1.f + erff(y3 * RS2));
    size_t ob = (((size_t)(b * 32 + o) * 128) + (2 * th + hh)) * 128 + 16 * tw + wb;
    float4 xv = *(const float4*)(x + ob);
    float4 r;
    r.x = g0 * xv.x; r.y = g1 * xv.y; r.z = g2 * xv.z; r.w = g3 * xv.w;
    *(float4*)(out + ob) = r;
  }
}

// ---------------------------------------------------------------------------
extern "C" void kernel_launch(void* const* d_in, const int* in_sizes, int n_in,
                              void* d_out, int out_size, void* d_ws, size_t ws_size,
                              hipStream_t stream) {
  const float* x  = (const float*)d_in[0];
  const float* w0 = (const float*)d_in[1];
  const float* b0 = (const float*)d_in[2];
  const float* w1 = (const float*)d_in[3];
  const float* b1 = (const float*)d_in[4];
  const float* w2 = (const float*)d_in[5];
  const float* b2 = (const float*)d_in[6];
  const float* wa = (const float*)d_in[7];
  const float* ba = (const float*)d_in[8];
  float* out = (float*)d_out;

  fused_safm<<<2048, 256, 0, stream>>>(x, w0, b0, w1, b1, w2, b2, wa, ba, out);
}